// Round 4
// baseline (991.886 us; speedup 1.0000x reference)
//
#include <hip/hip_runtime.h>
#include <math.h>

// Problem constants (from reference): B=2, N=2048, C=1024, H=4096, E=8, K=2
#define TT  4096      // tokens = B*N
#define CC  1024
#define HH  4096
#define EE  8
#define TKN 8192      // T*K total expert-row assignments
#define PGRID 1024    // persistent GEMM grid: 4 blocks/CU x 256 CU

typedef _Float16 f16x8 __attribute__((ext_vector_type(8)));
typedef float    f32x4 __attribute__((ext_vector_type(4)));

// async global->LDS DMA, 16B per lane; LDS dest = wave-uniform base + lane*16
#define GLD_LDS16(g, l)                                                        \
    __builtin_amdgcn_global_load_lds(                                          \
        (const __attribute__((address_space(1))) void*)(g),                    \
        (__attribute__((address_space(3))) void*)(l), 16, 0, 0)

// cheap exact-tailed GELU: gelu(v) = v - v/(exp(2y)+1), y = 0.79788456(v+0.044715v^3)
// (tanh-form; |err| vs erf-GELU < ~1.5e-3, threshold budget 4.4e-2)
__device__ __forceinline__ float fast_gelu(float v) {
    float y = 0.79788456080286536f * (v + 0.044715f * v * v * v);
    float ey = __expf(2.0f * y);
    return v - v / (ey + 1.0f);
}

// ---------------------------------------------------------------------------
// Kernel 1: gating. One wave per token. fp64 logits so top-2 selection matches
// the numpy reference (selection flips on near-ties would exceed threshold).
// ---------------------------------------------------------------------------
__global__ __launch_bounds__(256) void gate_kernel(
    const float* __restrict__ x, const float* __restrict__ gn,
    const float* __restrict__ gw, const float* __restrict__ gb,
    int* __restrict__ topk_idx, float* __restrict__ topk_w,
    int* __restrict__ counts, float* __restrict__ gsum)
{
    int wave = threadIdx.x >> 6, lane = threadIdx.x & 63;
    int t = blockIdx.x * 4 + wave;
    const float* xrow = x + (size_t)t * CC;

    double acc[EE];
#pragma unroll
    for (int e = 0; e < EE; e++) acc[e] = 0.0;

#pragma unroll
    for (int i = 0; i < CC / 64; i++) {
        int c = i * 64 + lane;
        float xv = xrow[c];                       // coalesced
        const float4* g4 = reinterpret_cast<const float4*>(gw + (size_t)c * EE);
        float4 g0 = g4[0], g1 = g4[1];            // gate_w row c (8 floats)
        double xd = (double)xv;
        acc[0] += xd * (double)g0.x; acc[1] += xd * (double)g0.y;
        acc[2] += xd * (double)g0.z; acc[3] += xd * (double)g0.w;
        acc[4] += xd * (double)g1.x; acc[5] += xd * (double)g1.y;
        acc[6] += xd * (double)g1.z; acc[7] += xd * (double)g1.w;
    }
#pragma unroll
    for (int e = 0; e < EE; e++)
#pragma unroll
        for (int off = 32; off > 0; off >>= 1)
            acc[e] += __shfl_xor(acc[e], off);

    double z[EE], m = -1e300;
#pragma unroll
    for (int e = 0; e < EE; e++) {
        z[e] = acc[e] + (double)gb[e] + (double)gn[(size_t)t * EE + e];
        m = fmax(m, z[e]);
    }
    double p[EE], s = 0.0;
#pragma unroll
    for (int e = 0; e < EE; e++) { p[e] = exp(z[e] - m); s += p[e]; }
    double inv = 1.0 / s;
    double g[EE];
#pragma unroll
    for (int e = 0; e < EE; e++) g[e] = p[e] * inv;

    int i1 = 0; double v1 = g[0];
#pragma unroll
    for (int e = 1; e < EE; e++) if (g[e] > v1) { v1 = g[e]; i1 = e; }
    int i2 = -1; double v2 = -1.0;
#pragma unroll
    for (int e = 0; e < EE; e++) if (e != i1 && g[e] > v2) { v2 = g[e]; i2 = e; }

    if (lane == 0) {
        topk_idx[t * 2 + 0] = i1; topk_w[t * 2 + 0] = (float)v1;
        topk_idx[t * 2 + 1] = i2; topk_w[t * 2 + 1] = (float)v2;
        atomicAdd(&counts[i1], 1);
        atomicAdd(&counts[i2], 1);
    }

    __shared__ float gp[4][EE];
    if (lane == 0) {
#pragma unroll
        for (int e = 0; e < EE; e++) gp[wave][e] = (float)g[e];
    }
    __syncthreads();
    if (threadIdx.x < EE) {
        float s4 = gp[0][threadIdx.x] + gp[1][threadIdx.x] +
                   gp[2][threadIdx.x] + gp[3][threadIdx.x];
        atomicAdd(&gsum[threadIdx.x], s4);
    }
}

// ---------------------------------------------------------------------------
// Kernel 2: fused transpose + f32->f16 cast for expert weights.
// src: [E][R][Ccols] f32 row-major  ->  dst: [E][Ccols][R] f16 row-major
// ---------------------------------------------------------------------------
__global__ __launch_bounds__(256) void transpose_f16_kernel(
    const float* __restrict__ src, _Float16* __restrict__ dst, int R, int Ccols)
{
    __shared__ float tile[64][65];
    int e = blockIdx.z;
    const float* s = src + (size_t)e * R * Ccols;
    _Float16* d = dst + (size_t)e * R * Ccols;
    int c0 = blockIdx.x * 64, r0 = blockIdx.y * 64;
    int tx = threadIdx.x, ty = threadIdx.y;
#pragma unroll
    for (int i = 0; i < 16; i++) {
        int r = ty + i * 4;
        tile[r][tx] = s[(size_t)(r0 + r) * Ccols + c0 + tx];
    }
    __syncthreads();
#pragma unroll
    for (int i = 0; i < 16; i++) {
        int c = ty + i * 4;
        d[(size_t)(c0 + c) * R + r0 + tx] = (_Float16)tile[tx][c];
    }
}

// ---------------------------------------------------------------------------
// Kernel 3: scan + tile-queue build (single block, 256 threads).
// tiles are m-innermost so consecutive tiles share their B-chunk (L2 reuse).
// ---------------------------------------------------------------------------
__global__ __launch_bounds__(256) void scan_kernel(
    const int* __restrict__ counts, int* __restrict__ offsets,
    const float* __restrict__ gsum, float* __restrict__ loss_out,
    int* __restrict__ tiles1, int* __restrict__ tiles2, int* __restrict__ ntl)
{
    __shared__ int s_mt[EE], s_tb1[EE], s_tb2[EE];
    int tid = threadIdx.x;
    if (tid == 0) {
        int o = 0, t1 = 0, t2 = 0;
#pragma unroll
        for (int e = 0; e < EE; e++) {
            offsets[e] = o;
            int mt = (counts[e] + 127) >> 7;
            s_mt[e] = mt; s_tb1[e] = t1; s_tb2[e] = t2;
            o += counts[e]; t1 += mt * (HH / 128); t2 += mt * 2 * (CC / 128);
        }
        offsets[EE] = o;
        ntl[0] = t1; ntl[1] = t2;
        float L = 0.f;
#pragma unroll
        for (int e = 0; e < EE; e++) {
            float me = gsum[e] / (float)TT;
            L += me * logf(me + 1e-8f);
        }
        *loss_out = L;
    }
    __syncthreads();
    {   // tiles1: 8 experts x 32 n-tiles = 256 threads
        int e = tid >> 5, n = tid & 31;
        int base = s_tb1[e] + n * s_mt[e];
        for (int m = 0; m < s_mt[e]; m++)
            tiles1[base + m] = (e << 20) | (n << 12) | m;
    }
    if (tid < 128) {  // tiles2: 8 experts x 16 (kz,n) combos
        int e = tid >> 4, nk = tid & 15;
        int base = s_tb2[e] + nk * s_mt[e];
        for (int m = 0; m < s_mt[e]; m++)
            tiles2[base + m] = (e << 20) | (nk << 12) | m;
    }
}

// ---------------------------------------------------------------------------
// Kernel 4: scatter token assignments into per-expert contiguous segments.
// Also records the inverse map posmap[t*2+k] for the combine kernel.
// ---------------------------------------------------------------------------
__global__ __launch_bounds__(256) void scatter_kernel(
    const int* __restrict__ topk_idx, const float* __restrict__ topk_w,
    const int* __restrict__ offsets, int* __restrict__ fill,
    int* __restrict__ rowtok, float* __restrict__ rweight,
    int* __restrict__ posmap)
{
    int t = blockIdx.x * 256 + threadIdx.x;
#pragma unroll
    for (int k = 0; k < 2; k++) {
        int e = topk_idx[t * 2 + k];
        int pos = offsets[e] + atomicAdd(&fill[e], 1);
        rowtok[pos] = t;
        rweight[pos] = topk_w[t * 2 + k];
        posmap[t * 2 + k] = pos;
    }
}

// ---------------------------------------------------------------------------
// Kernel 5: pre-gather token rows into segment order + f32->f16 cast.
// ---------------------------------------------------------------------------
__global__ __launch_bounds__(256) void gather_kernel(
    const float* __restrict__ x, const int* __restrict__ rowtok,
    _Float16* __restrict__ xg)
{
    int p = blockIdx.x * 2 + (threadIdx.x >> 7);
    int c = (threadIdx.x & 127) * 8;
    int t = rowtok[p];
    const float4* s = reinterpret_cast<const float4*>(x + (size_t)t * CC + c);
    float4 v0 = s[0], v1 = s[1];
    f16x8 o;
    o[0] = (_Float16)v0.x; o[1] = (_Float16)v0.y;
    o[2] = (_Float16)v0.z; o[3] = (_Float16)v0.w;
    o[4] = (_Float16)v1.x; o[5] = (_Float16)v1.y;
    o[6] = (_Float16)v1.z; o[7] = (_Float16)v1.w;
    *reinterpret_cast<f16x8*>(xg + (size_t)p * CC + c) = o;
}

// ---------------------------------------------------------------------------
// Persistent grouped GEMM 1: h[p,:] = gelu( xg[p,:] @ w1[e] + b1[e] )
// Ticket-scheduled: each block atomically grabs the next tile (perfect balance,
// in-order consumption keeps the shared B-chunk hot in L2).
// ---------------------------------------------------------------------------
__global__ __launch_bounds__(256, 4) void gemm1_kernel(
    const _Float16* __restrict__ xg, const _Float16* __restrict__ w1t,
    const float* __restrict__ b1, const int* __restrict__ offsets,
    const int* __restrict__ tiles, const int* __restrict__ ntl,
    int* __restrict__ ticket, _Float16* __restrict__ h)
{
    __shared__ __align__(16) _Float16 As[128][64];
    __shared__ __align__(16) _Float16 Bs[128][64];
    __shared__ int sh_ti;

    int nt = ntl[0];
    int tid = threadIdx.x;
    int wave = tid >> 6, lane = tid & 63;
    int wm = (wave >> 1) * 64, wn = (wave & 1) * 64;
    int lrow = lane & 15, kg = lane >> 4;
    int ch0 = wave * 4 * 64 + lane;
    int rbase = (lane >> 4) * 4;

    for (;;) {
        if (tid == 0) sh_ti = atomicAdd(ticket, 1);
        __syncthreads();            // publishes sh_ti; also fences LDS reuse
        int ti = sh_ti;
        if (ti >= nt) break;

        int id = tiles[ti];
        int e = id >> 20, n0 = ((id >> 12) & 0xFF) * 128, m0 = (id & 0xFFF) * 128;
        int segs = offsets[e];
        int M = offsets[e + 1] - segs;
        const _Float16* wB = w1t + (size_t)e * HH * CC;

        const _Float16* ap[4]; const _Float16* bp[4];
        _Float16 *al[4], *bl[4];
#pragma unroll
        for (int j = 0; j < 4; j++) {
            int ch = ch0 + j * 64;
            int row = ch >> 3, kc = ch & 7;
            int rm = m0 + row; if (rm >= M) rm = M - 1;
            ap[j] = xg + (size_t)(segs + rm) * CC + kc * 8;
            bp[j] = wB + (size_t)(n0 + row) * CC + kc * 8;
            al[j] = &As[0][0] + ch * 8;
            bl[j] = &Bs[0][0] + ch * 8;
        }

        f32x4 acc[4][4];
#pragma unroll
        for (int i = 0; i < 4; i++)
#pragma unroll
            for (int j = 0; j < 4; j++)
#pragma unroll
                for (int r = 0; r < 4; r++) acc[i][j][r] = 0.f;

        for (int k0 = 0; k0 < CC; k0 += 64) {
#pragma unroll
            for (int j = 0; j < 4; j++) {
                GLD_LDS16(ap[j], al[j]);
                GLD_LDS16(bp[j], bl[j]);
                ap[j] += 64; bp[j] += 64;
            }
            __syncthreads();

            f16x8 aF[2][4], bF[2][4];
#pragma unroll
            for (int s = 0; s < 2; s++)
#pragma unroll
                for (int i = 0; i < 4; i++) {
                    aF[s][i] = *reinterpret_cast<const f16x8*>(
                        &As[wm + i * 16 + lrow][s * 32 + kg * 8]);
                    bF[s][i] = *reinterpret_cast<const f16x8*>(
                        &Bs[wn + i * 16 + lrow][s * 32 + kg * 8]);
                }
#pragma unroll
            for (int s = 0; s < 2; s++)
#pragma unroll
                for (int mi = 0; mi < 4; mi++)
#pragma unroll
                    for (int ni = 0; ni < 4; ni++)
                        acc[mi][ni] = __builtin_amdgcn_mfma_f32_16x16x32_f16(
                            aF[s][mi], bF[s][ni], acc[mi][ni], 0, 0, 0);
            __syncthreads();
        }

        // epilogue: C/D layout col=lane&15, row=(lane>>4)*4+reg  [m89/m91]
#pragma unroll
        for (int mi = 0; mi < 4; mi++) {
#pragma unroll
            for (int ni = 0; ni < 4; ni++) {
                int gcol = n0 + wn + ni * 16 + lrow;
                float bias = b1[(size_t)e * HH + gcol];
#pragma unroll
                for (int r = 0; r < 4; r++) {
                    int rowl = m0 + wm + mi * 16 + rbase + r;
                    if (rowl < M) {
                        float v = fast_gelu(acc[mi][ni][r] + bias);
                        h[(size_t)(segs + rowl) * HH + gcol] = (_Float16)v;
                    }
                }
            }
        }
    }
}

// ---------------------------------------------------------------------------
// Persistent grouped GEMM 2 (split-K=2), ticket-scheduled.
// ybuf path (no atomics): yk[kz][p][:] = h[p,:] @ w2[e](half-K) + (kz==0)*b2
// fallback (ybuf==nullptr): atomicAdd weighted result into out directly.
// ---------------------------------------------------------------------------
__global__ __launch_bounds__(256, 4) void gemm2_kernel(
    const _Float16* __restrict__ h, const _Float16* __restrict__ w2t,
    const float* __restrict__ b2, const int* __restrict__ rowtok,
    const float* __restrict__ rweight, const int* __restrict__ offsets,
    const int* __restrict__ tiles, const int* __restrict__ ntl,
    int* __restrict__ ticket, float* __restrict__ ybuf, float* __restrict__ out)
{
    __shared__ __align__(16) _Float16 As[128][64];
    __shared__ __align__(16) _Float16 Bs[128][64];
    __shared__ int toks[128];
    __shared__ float wgt[128];
    __shared__ int sh_ti;

    int nt = ntl[1];
    int tid = threadIdx.x;
    int wave = tid >> 6, lane = tid & 63;
    int wm = (wave >> 1) * 64, wn = (wave & 1) * 64;
    int lrow = lane & 15, kg = lane >> 4;
    int ch0 = wave * 4 * 64 + lane;
    int rbase = (lane >> 4) * 4;

    for (;;) {
        if (tid == 0) sh_ti = atomicAdd(ticket, 1);
        __syncthreads();
        int ti = sh_ti;
        if (ti >= nt) break;

        int id = tiles[ti];
        int e = id >> 20, nk = (id >> 12) & 0xFF, m0 = (id & 0xFFF) * 128;
        int kz = nk >> 3, n0 = (nk & 7) * 128;
        int segs = offsets[e];
        int M = offsets[e + 1] - segs;
        const _Float16* wB = w2t + (size_t)e * CC * HH;
        int kbeg = kz * (HH / 2);

        if (!ybuf && tid < 128) {       // atomic fallback needs token map
            int r = m0 + tid;
            int rr = (r < M) ? r : (M - 1);
            toks[tid] = rowtok[segs + rr];
            wgt[tid] = rweight[segs + rr];
        }

        const _Float16* ap[4]; const _Float16* bp[4];
        _Float16 *al[4], *bl[4];
#pragma unroll
        for (int j = 0; j < 4; j++) {
            int ch = ch0 + j * 64;
            int row = ch >> 3, kc = ch & 7;
            int rm = m0 + row; if (rm >= M) rm = M - 1;
            ap[j] = h  + (size_t)(segs + rm) * HH + kbeg + kc * 8;
            bp[j] = wB + (size_t)(n0 + row) * HH + kbeg + kc * 8;
            al[j] = &As[0][0] + ch * 8;
            bl[j] = &Bs[0][0] + ch * 8;
        }

        f32x4 acc[4][4];
#pragma unroll
        for (int i = 0; i < 4; i++)
#pragma unroll
            for (int j = 0; j < 4; j++)
#pragma unroll
                for (int r = 0; r < 4; r++) acc[i][j][r] = 0.f;

        for (int k0 = 0; k0 < HH / 2; k0 += 64) {
#pragma unroll
            for (int j = 0; j < 4; j++) {
                GLD_LDS16(ap[j], al[j]);
                GLD_LDS16(bp[j], bl[j]);
                ap[j] += 64; bp[j] += 64;
            }
            __syncthreads();

            f16x8 aF[2][4], bF[2][4];
#pragma unroll
            for (int s = 0; s < 2; s++)
#pragma unroll
                for (int i = 0; i < 4; i++) {
                    aF[s][i] = *reinterpret_cast<const f16x8*>(
                        &As[wm + i * 16 + lrow][s * 32 + kg * 8]);
                    bF[s][i] = *reinterpret_cast<const f16x8*>(
                        &Bs[wn + i * 16 + lrow][s * 32 + kg * 8]);
                }
#pragma unroll
            for (int s = 0; s < 2; s++)
#pragma unroll
                for (int mi = 0; mi < 4; mi++)
#pragma unroll
                    for (int ni = 0; ni < 4; ni++)
                        acc[mi][ni] = __builtin_amdgcn_mfma_f32_16x16x32_f16(
                            aF[s][mi], bF[s][ni], acc[mi][ni], 0, 0, 0);
            __syncthreads();
        }

#pragma unroll
        for (int mi = 0; mi < 4; mi++) {
#pragma unroll
            for (int ni = 0; ni < 4; ni++) {
                int gcol = n0 + wn + ni * 16 + lrow;
                float bias = (kz == 0) ? b2[(size_t)e * CC + gcol] : 0.f;
#pragma unroll
                for (int r = 0; r < 4; r++) {
                    int rowl = m0 + wm + mi * 16 + rbase + r;
                    if (rowl < M) {
                        float v = acc[mi][ni][r] + bias;
                        if (ybuf) {
                            ybuf[((size_t)kz * TKN + segs + rowl) * CC + gcol] = v;
                        } else {
                            int lr = rowl - m0;
                            unsafeAtomicAdd(&out[(size_t)toks[lr] * CC + gcol],
                                            v * wgt[lr]);
                        }
                    }
                }
            }
        }
    }
}

// ---------------------------------------------------------------------------
// Kernel 7: combine. out[t,:] = sum_k topk_w[t,k] * (y0[p_k,:] + y1[p_k,:])
// Fully overwrites out (no memset needed). Deterministic, no atomics.
// ---------------------------------------------------------------------------
__global__ __launch_bounds__(256) void combine_kernel(
    const float* __restrict__ ybuf, const int* __restrict__ posmap,
    const float* __restrict__ topk_w, float* __restrict__ out)
{
    int t = blockIdx.x * 2 + (threadIdx.x >> 7);
    int c = (threadIdx.x & 127) * 8;
    int p1 = posmap[t * 2 + 0], p2 = posmap[t * 2 + 1];
    float w1 = topk_w[t * 2 + 0], w2 = topk_w[t * 2 + 1];
    const float4* y0a = reinterpret_cast<const float4*>(ybuf + (size_t)p1 * CC + c);
    const float4* y1a = reinterpret_cast<const float4*>(ybuf + ((size_t)TKN + p1) * CC + c);
    const float4* y0b = reinterpret_cast<const float4*>(ybuf + (size_t)p2 * CC + c);
    const float4* y1b = reinterpret_cast<const float4*>(ybuf + ((size_t)TKN + p2) * CC + c);
    float4* o = reinterpret_cast<float4*>(out + (size_t)t * CC + c);
#pragma unroll
    for (int i = 0; i < 2; i++) {
        float4 a0 = y0a[i], a1 = y1a[i], b0 = y0b[i], b1 = y1b[i];
        float4 r;
        r.x = w1 * (a0.x + a1.x) + w2 * (b0.x + b1.x);
        r.y = w1 * (a0.y + a1.y) + w2 * (b0.y + b1.y);
        r.z = w1 * (a0.z + a1.z) + w2 * (b0.z + b1.z);
        r.w = w1 * (a0.w + a1.w) + w2 * (b0.w + b1.w);
        o[i] = r;
    }
}

// ---------------------------------------------------------------------------
extern "C" void kernel_launch(void* const* d_in, const int* in_sizes, int n_in,
                              void* d_out, int out_size, void* d_ws, size_t ws_size,
                              hipStream_t stream)
{
    const float* x  = (const float*)d_in[0];
    const float* gn = (const float*)d_in[1];
    const float* gw = (const float*)d_in[2];
    const float* gb = (const float*)d_in[3];
    const float* w1 = (const float*)d_in[4];
    const float* b1 = (const float*)d_in[5];
    const float* w2 = (const float*)d_in[6];
    const float* b2 = (const float*)d_in[7];
    float* out = (float*)d_out;

    // workspace carve (16B-aligned)
    char* w = (char*)d_ws;
    int*   counts  = (int*)(w + 0);     // 8 ints
    int*   fill    = (int*)(w + 32);    // 8 ints
    int*   offsets = (int*)(w + 64);    // 9 ints
    float* gsum    = (float*)(w + 128); // 8 floats
    int*   ntl     = (int*)(w + 192);   // 2 ints
    int*   tick1   = (int*)(w + 200);
    int*   tick2   = (int*)(w + 204);
    size_t off = 256;
    int*   topk_idx = (int*)(w + off);   off += (size_t)TT * 2 * 4;
    float* topk_w   = (float*)(w + off); off += (size_t)TT * 2 * 4;
    int*   rowtok   = (int*)(w + off);   off += (size_t)TKN * 4;
    float* rweight  = (float*)(w + off); off += (size_t)TKN * 4;
    int*   posmap   = (int*)(w + off);   off += (size_t)TKN * 4;
    int*   tiles1   = (int*)(w + off);   off += 4096 * 4;
    int*   tiles2   = (int*)(w + off);   off += 2048 * 4;
    _Float16* xg  = (_Float16*)(w + off); off += (size_t)TKN * CC * 2;      // 16 MB
    _Float16* w1t = (_Float16*)(w + off); off += (size_t)EE * HH * CC * 2;  // 64 MB
    _Float16* w2t = (_Float16*)(w + off); off += (size_t)EE * CC * HH * 2;  // 64 MB
    _Float16* hbuf = (_Float16*)(w + off); off += (size_t)TKN * HH * 2;     // 64 MB
    float* ybuf = (float*)(w + off);
    size_t need = off + (size_t)2 * TKN * CC * 4;                           // +64 MB
    bool use_ybuf = (ws_size >= need);
    if (!use_ybuf) ybuf = nullptr;

    (void)hipMemsetAsync(d_ws, 0, 256, stream);
    if (!use_ybuf)   // atomic fallback accumulates into out
        (void)hipMemsetAsync(d_out, 0, (size_t)out_size * sizeof(float), stream);

    gate_kernel<<<TT / 4, 256, 0, stream>>>(x, gn, gw, gb, topk_idx, topk_w,
                                            counts, gsum);
    // w1 [E,C,H] -> w1t [E,H,C];  w2 [E,H,C] -> w2t [E,C,H]
    transpose_f16_kernel<<<dim3(HH / 64, CC / 64, EE), dim3(64, 4), 0, stream>>>(
        w1, w1t, CC, HH);
    transpose_f16_kernel<<<dim3(CC / 64, HH / 64, EE), dim3(64, 4), 0, stream>>>(
        w2, w2t, HH, CC);
    scan_kernel<<<1, 256, 0, stream>>>(counts, offsets, gsum,
                                       out + (size_t)TT * CC, tiles1, tiles2, ntl);
    scatter_kernel<<<TT / 256, 256, 0, stream>>>(topk_idx, topk_w, offsets, fill,
                                                 rowtok, rweight, posmap);
    gather_kernel<<<TKN / 2, 256, 0, stream>>>(x, rowtok, xg);
    gemm1_kernel<<<PGRID, 256, 0, stream>>>(xg, w1t, b1, offsets, tiles1, ntl,
                                            tick1, hbuf);
    gemm2_kernel<<<PGRID, 256, 0, stream>>>(hbuf, w2t, b2, rowtok, rweight,
                                            offsets, tiles2, ntl, tick2, ybuf, out);
    if (use_ybuf)
        combine_kernel<<<TT / 2, 256, 0, stream>>>(ybuf, posmap, topk_w, out);
}

// Round 5
// 969.301 us; speedup vs baseline: 1.0233x; 1.0233x over previous
//
#include <hip/hip_runtime.h>
#include <math.h>

// Problem constants (from reference): B=2, N=2048, C=1024, H=4096, E=8, K=2
#define TT  4096      // tokens = B*N
#define CC  1024
#define HH  4096
#define EE  8
#define TKN 8192      // T*K total expert-row assignments
#define GGRID 256     // persistent GEMM grid: 1 block/CU (512 threads = 8 waves)

typedef _Float16 f16x8 __attribute__((ext_vector_type(8)));
typedef float    f32x4 __attribute__((ext_vector_type(4)));

// async global->LDS DMA, 16B per lane; LDS dest = wave-uniform base + lane*16
#define GLD_LDS16(g, l)                                                        \
    __builtin_amdgcn_global_load_lds(                                          \
        (const __attribute__((address_space(1))) void*)(g),                    \
        (__attribute__((address_space(3))) void*)(l), 16, 0, 0)

// cheap exact-tailed GELU: gelu(v) ~= v - v/(exp(2y)+1), y = 0.79788456(v+0.044715v^3)
__device__ __forceinline__ float fast_gelu(float v) {
    float y = 0.79788456080286536f * (v + 0.044715f * v * v * v);
    float ey = __expf(2.0f * y);
    return v - v / (ey + 1.0f);
}

// ---------------------------------------------------------------------------
// Kernel 1: gating. One wave per token, fp64 logits (top-2 selection must
// match the numpy reference bit-for-bit on near-ties).
// ---------------------------------------------------------------------------
__global__ __launch_bounds__(256) void gate_kernel(
    const float* __restrict__ x, const float* __restrict__ gn,
    const float* __restrict__ gw, const float* __restrict__ gb,
    int* __restrict__ topk_idx, float* __restrict__ topk_w,
    int* __restrict__ counts, float* __restrict__ gsum)
{
    int wave = threadIdx.x >> 6, lane = threadIdx.x & 63;
    int t = blockIdx.x * 4 + wave;
    const float* xrow = x + (size_t)t * CC;

    double acc[EE];
#pragma unroll
    for (int e = 0; e < EE; e++) acc[e] = 0.0;

#pragma unroll
    for (int i = 0; i < CC / 64; i++) {
        int c = i * 64 + lane;
        float xv = xrow[c];
        const float4* g4 = reinterpret_cast<const float4*>(gw + (size_t)c * EE);
        float4 g0 = g4[0], g1 = g4[1];
        double xd = (double)xv;
        acc[0] += xd * (double)g0.x; acc[1] += xd * (double)g0.y;
        acc[2] += xd * (double)g0.z; acc[3] += xd * (double)g0.w;
        acc[4] += xd * (double)g1.x; acc[5] += xd * (double)g1.y;
        acc[6] += xd * (double)g1.z; acc[7] += xd * (double)g1.w;
    }
#pragma unroll
    for (int e = 0; e < EE; e++)
#pragma unroll
        for (int off = 32; off > 0; off >>= 1)
            acc[e] += __shfl_xor(acc[e], off);

    double z[EE], m = -1e300;
#pragma unroll
    for (int e = 0; e < EE; e++) {
        z[e] = acc[e] + (double)gb[e] + (double)gn[(size_t)t * EE + e];
        m = fmax(m, z[e]);
    }
    double p[EE], s = 0.0;
#pragma unroll
    for (int e = 0; e < EE; e++) { p[e] = exp(z[e] - m); s += p[e]; }
    double inv = 1.0 / s;
    double g[EE];
#pragma unroll
    for (int e = 0; e < EE; e++) g[e] = p[e] * inv;

    int i1 = 0; double v1 = g[0];
#pragma unroll
    for (int e = 1; e < EE; e++) if (g[e] > v1) { v1 = g[e]; i1 = e; }
    int i2 = -1; double v2 = -1.0;
#pragma unroll
    for (int e = 0; e < EE; e++) if (e != i1 && g[e] > v2) { v2 = g[e]; i2 = e; }

    if (lane == 0) {
        topk_idx[t * 2 + 0] = i1; topk_w[t * 2 + 0] = (float)v1;
        topk_idx[t * 2 + 1] = i2; topk_w[t * 2 + 1] = (float)v2;
        atomicAdd(&counts[i1], 1);
        atomicAdd(&counts[i2], 1);
    }

    __shared__ float gp[4][EE];
    if (lane == 0) {
#pragma unroll
        for (int e = 0; e < EE; e++) gp[wave][e] = (float)g[e];
    }
    __syncthreads();
    if (threadIdx.x < EE) {
        float s4 = gp[0][threadIdx.x] + gp[1][threadIdx.x] +
                   gp[2][threadIdx.x] + gp[3][threadIdx.x];
        atomicAdd(&gsum[threadIdx.x], s4);
    }
}

// ---------------------------------------------------------------------------
// Kernel 2: fused transpose + f32->f16 cast for expert weights (vectorized).
// src: [E][R][Ccols] f32 row-major  ->  dst: [E][Ccols][R] f16 row-major
// 64x64 tile, 256 flat threads; float4 loads, f16x8 stores.
// ---------------------------------------------------------------------------
__global__ __launch_bounds__(256) void transpose_f16_kernel(
    const float* __restrict__ src, _Float16* __restrict__ dst, int R, int Ccols)
{
    __shared__ float tile[64][65];
    int e = blockIdx.z;
    const float* s = src + (size_t)e * R * Ccols;
    _Float16* d = dst + (size_t)e * R * Ccols;
    int c0 = blockIdx.x * 64, r0 = blockIdx.y * 64;
    int tid = threadIdx.x;
#pragma unroll
    for (int i = 0; i < 4; i++) {
        int idx = i * 256 + tid;
        int r = idx >> 4, c4 = (idx & 15) * 4;
        float4 v = *reinterpret_cast<const float4*>(
            s + (size_t)(r0 + r) * Ccols + c0 + c4);
        tile[r][c4 + 0] = v.x; tile[r][c4 + 1] = v.y;
        tile[r][c4 + 2] = v.z; tile[r][c4 + 3] = v.w;
    }
    __syncthreads();
#pragma unroll
    for (int i = 0; i < 2; i++) {
        int idx = i * 256 + tid;
        int c = idx >> 3, s8 = (idx & 7) * 8;
        f16x8 o;
#pragma unroll
        for (int j = 0; j < 8; j++) o[j] = (_Float16)tile[s8 + j][c];
        *reinterpret_cast<f16x8*>(d + (size_t)(c0 + c) * R + r0 + s8) = o;
    }
}

// ---------------------------------------------------------------------------
// Kernel 3: scan + tile-list build (single block, 256 threads). 256x256 tiles.
// tiles1: (e, n in 0..15, m) ; tiles2: (e, nk = kz*4+n in 0..7, m)
// ---------------------------------------------------------------------------
__global__ __launch_bounds__(256) void scan_kernel(
    const int* __restrict__ counts, int* __restrict__ offsets,
    const float* __restrict__ gsum, float* __restrict__ loss_out,
    int* __restrict__ tiles1, int* __restrict__ tiles2, int* __restrict__ ntl)
{
    __shared__ int s_mt[EE], s_tb1[EE], s_tb2[EE];
    int tid = threadIdx.x;
    if (tid == 0) {
        int o = 0, t1 = 0, t2 = 0;
#pragma unroll
        for (int e = 0; e < EE; e++) {
            offsets[e] = o;
            int mt = (counts[e] + 255) >> 8;          // 256-row m-chunks
            s_mt[e] = mt; s_tb1[e] = t1; s_tb2[e] = t2;
            o += counts[e]; t1 += mt * (HH / 256); t2 += mt * 2 * (CC / 256);
        }
        offsets[EE] = o;
        ntl[0] = t1; ntl[1] = t2;
        float L = 0.f;
#pragma unroll
        for (int e = 0; e < EE; e++) {
            float me = gsum[e] / (float)TT;
            L += me * logf(me + 1e-8f);
        }
        *loss_out = L;
    }
    __syncthreads();
    if (tid < 128) {  // tiles1: 8 e x 16 n
        int e = tid >> 4, n = tid & 15;
        int base = s_tb1[e] + n * s_mt[e];
        for (int m = 0; m < s_mt[e]; m++)
            tiles1[base + m] = (e << 20) | (n << 12) | m;
    }
    if (tid < 64) {   // tiles2: 8 e x 8 nk (kz*4+n)
        int e = tid >> 3, nk = tid & 7;
        int base = s_tb2[e] + nk * s_mt[e];
        for (int m = 0; m < s_mt[e]; m++)
            tiles2[base + m] = (e << 20) | (nk << 12) | m;
    }
}

// ---------------------------------------------------------------------------
// Kernel 4: scatter token assignments into per-expert contiguous segments.
// ---------------------------------------------------------------------------
__global__ __launch_bounds__(256) void scatter_kernel(
    const int* __restrict__ topk_idx, const float* __restrict__ topk_w,
    const int* __restrict__ offsets, int* __restrict__ fill,
    int* __restrict__ rowtok, float* __restrict__ rweight)
{
    int t = blockIdx.x * 256 + threadIdx.x;
#pragma unroll
    for (int k = 0; k < 2; k++) {
        int e = topk_idx[t * 2 + k];
        int pos = offsets[e] + atomicAdd(&fill[e], 1);
        rowtok[pos] = t;
        rweight[pos] = topk_w[t * 2 + k];
    }
}

// ---------------------------------------------------------------------------
// Kernel 5: pre-gather token rows into segment order + f32->f16 cast.
// ---------------------------------------------------------------------------
__global__ __launch_bounds__(256) void gather_kernel(
    const float* __restrict__ x, const int* __restrict__ rowtok,
    _Float16* __restrict__ xg)
{
    int p = blockIdx.x * 2 + (threadIdx.x >> 7);
    int c = (threadIdx.x & 127) * 8;
    int t = rowtok[p];
    const float4* s = reinterpret_cast<const float4*>(x + (size_t)t * CC + c);
    float4 v0 = s[0], v1 = s[1];
    f16x8 o;
    o[0] = (_Float16)v0.x; o[1] = (_Float16)v0.y;
    o[2] = (_Float16)v0.z; o[3] = (_Float16)v0.w;
    o[4] = (_Float16)v1.x; o[5] = (_Float16)v1.y;
    o[6] = (_Float16)v1.z; o[7] = (_Float16)v1.w;
    *reinterpret_cast<f16x8*>(xg + (size_t)p * CC + c) = o;
}

// ---------------------------------------------------------------------------
// Persistent grouped GEMM 1: h[p,:] = gelu( xg[p,:] @ w1[e] + b1[e] )
// 256x256 tile, 512 threads (8 waves = 4m x 2n of 64x128), BK=64, m97 K-loop.
// Halves per-tile restage traffic vs 128x128 (the measured 3.2 TB/s limiter).
// ---------------------------------------------------------------------------
__global__ __launch_bounds__(512, 2) void gemm1_kernel(
    const _Float16* __restrict__ xg, const _Float16* __restrict__ w1t,
    const float* __restrict__ b1, const int* __restrict__ offsets,
    const int* __restrict__ tiles, const int* __restrict__ ntl,
    _Float16* __restrict__ h)
{
    __shared__ __align__(16) _Float16 As[256][64];
    __shared__ __align__(16) _Float16 Bs[256][64];

    int nt = ntl[0];
    int tid = threadIdx.x;
    int wave = tid >> 6, lane = tid & 63;
    int wm = (wave >> 1) * 64, wn = (wave & 1) * 128;
    int lrow = lane & 15, kg = lane >> 4;
    int ch0 = wave * 256 + lane;    // this wave's first of 4 chunks per matrix
    int rbase = (lane >> 4) * 4;

    for (int ti = blockIdx.x; ti < nt; ti += gridDim.x) {
        int id = tiles[ti];
        int e = id >> 20, n0 = ((id >> 12) & 0xFF) * 256, m0 = (id & 0xFFF) * 256;
        int segs = offsets[e];
        int M = offsets[e + 1] - segs;
        const _Float16* wB = w1t + (size_t)e * HH * CC;

        const _Float16* ap[4]; const _Float16* bp[4];
        _Float16 *al[4], *bl[4];
#pragma unroll
        for (int j = 0; j < 4; j++) {
            int ch = ch0 + j * 64;          // 0..2047
            int row = ch >> 3, kc = ch & 7;
            int rm = m0 + row; if (rm >= M) rm = M - 1;   // clamp inside segment
            ap[j] = xg + (size_t)(segs + rm) * CC + kc * 8;
            bp[j] = wB + (size_t)(n0 + row) * CC + kc * 8;
            al[j] = &As[0][0] + ch * 8;
            bl[j] = &Bs[0][0] + ch * 8;
        }

        f32x4 acc[4][8];
#pragma unroll
        for (int i = 0; i < 4; i++)
#pragma unroll
            for (int j = 0; j < 8; j++)
#pragma unroll
                for (int r = 0; r < 4; r++) acc[i][j][r] = 0.f;

        for (int k0 = 0; k0 < CC; k0 += 64) {
#pragma unroll
            for (int j = 0; j < 4; j++) {
                GLD_LDS16(ap[j], al[j]);
                GLD_LDS16(bp[j], bl[j]);
                ap[j] += 64; bp[j] += 64;
            }
            __syncthreads();

#pragma unroll
            for (int s = 0; s < 2; s++) {
                f16x8 aF[4], bF[8];
#pragma unroll
                for (int i = 0; i < 4; i++)
                    aF[i] = *reinterpret_cast<const f16x8*>(
                        &As[wm + i * 16 + lrow][s * 32 + kg * 8]);
#pragma unroll
                for (int i = 0; i < 8; i++)
                    bF[i] = *reinterpret_cast<const f16x8*>(
                        &Bs[wn + i * 16 + lrow][s * 32 + kg * 8]);
#pragma unroll
                for (int mi = 0; mi < 4; mi++)
#pragma unroll
                    for (int ni = 0; ni < 8; ni++)
                        acc[mi][ni] = __builtin_amdgcn_mfma_f32_16x16x32_f16(
                            aF[mi], bF[ni], acc[mi][ni], 0, 0, 0);
            }
            __syncthreads();
        }

        // epilogue: C/D layout col=lane&15, row=(lane>>4)*4+reg  [m89/m91]
#pragma unroll
        for (int mi = 0; mi < 4; mi++) {
#pragma unroll
            for (int ni = 0; ni < 8; ni++) {
                int gcol = n0 + wn + ni * 16 + lrow;
                float bias = b1[(size_t)e * HH + gcol];
#pragma unroll
                for (int r = 0; r < 4; r++) {
                    int rowl = m0 + wm + mi * 16 + rbase + r;
                    if (rowl < M) {
                        float v = fast_gelu(acc[mi][ni][r] + bias);
                        h[(size_t)(segs + rowl) * HH + gcol] = (_Float16)v;
                    }
                }
            }
        }
        // epilogue reads registers only; trailing K-loop barrier covers LDS.
    }
}

// ---------------------------------------------------------------------------
// Persistent grouped GEMM 2 (split-K=2), 256x256 tiles, atomic epilogue:
// out[tok(p),:] += w(p) * ( h[p,:] @ w2[e](half-K) + (kz==0)*b2[e] )
// ---------------------------------------------------------------------------
__global__ __launch_bounds__(512, 2) void gemm2_kernel(
    const _Float16* __restrict__ h, const _Float16* __restrict__ w2t,
    const float* __restrict__ b2, const int* __restrict__ rowtok,
    const float* __restrict__ rweight, const int* __restrict__ offsets,
    const int* __restrict__ tiles, const int* __restrict__ ntl,
    float* __restrict__ out)
{
    __shared__ __align__(16) _Float16 As[256][64];
    __shared__ __align__(16) _Float16 Bs[256][64];
    __shared__ int toks[256];
    __shared__ float wgt[256];

    int nt = ntl[1];
    int tid = threadIdx.x;
    int wave = tid >> 6, lane = tid & 63;
    int wm = (wave >> 1) * 64, wn = (wave & 1) * 128;
    int lrow = lane & 15, kg = lane >> 4;
    int ch0 = wave * 256 + lane;
    int rbase = (lane >> 4) * 4;

    for (int ti = blockIdx.x; ti < nt; ti += gridDim.x) {
        __syncthreads();   // protect prev tile's epilogue reads of toks/wgt
        int id = tiles[ti];
        int e = id >> 20, nk = (id >> 12) & 0xFF, m0 = (id & 0xFFF) * 256;
        int kz = nk >> 2, n0 = (nk & 3) * 256;
        int segs = offsets[e];
        int M = offsets[e + 1] - segs;
        const _Float16* wB = w2t + (size_t)e * CC * HH;
        int kbeg = kz * (HH / 2);

        if (tid < 256) {
            int r = m0 + tid;
            int rr = (r < M) ? r : (M - 1);
            toks[tid] = rowtok[segs + rr];
            wgt[tid] = rweight[segs + rr];
        }

        const _Float16* ap[4]; const _Float16* bp[4];
        _Float16 *al[4], *bl[4];
#pragma unroll
        for (int j = 0; j < 4; j++) {
            int ch = ch0 + j * 64;
            int row = ch >> 3, kc = ch & 7;
            int rm = m0 + row; if (rm >= M) rm = M - 1;
            ap[j] = h  + (size_t)(segs + rm) * HH + kbeg + kc * 8;
            bp[j] = wB + (size_t)(n0 + row) * HH + kbeg + kc * 8;
            al[j] = &As[0][0] + ch * 8;
            bl[j] = &Bs[0][0] + ch * 8;
        }

        f32x4 acc[4][8];
#pragma unroll
        for (int i = 0; i < 4; i++)
#pragma unroll
            for (int j = 0; j < 8; j++)
#pragma unroll
                for (int r = 0; r < 4; r++) acc[i][j][r] = 0.f;

        for (int k0 = 0; k0 < HH / 2; k0 += 64) {
#pragma unroll
            for (int j = 0; j < 4; j++) {
                GLD_LDS16(ap[j], al[j]);
                GLD_LDS16(bp[j], bl[j]);
                ap[j] += 64; bp[j] += 64;
            }
            __syncthreads();

#pragma unroll
            for (int s = 0; s < 2; s++) {
                f16x8 aF[4], bF[8];
#pragma unroll
                for (int i = 0; i < 4; i++)
                    aF[i] = *reinterpret_cast<const f16x8*>(
                        &As[wm + i * 16 + lrow][s * 32 + kg * 8]);
#pragma unroll
                for (int i = 0; i < 8; i++)
                    bF[i] = *reinterpret_cast<const f16x8*>(
                        &Bs[wn + i * 16 + lrow][s * 32 + kg * 8]);
#pragma unroll
                for (int mi = 0; mi < 4; mi++)
#pragma unroll
                    for (int ni = 0; ni < 8; ni++)
                        acc[mi][ni] = __builtin_amdgcn_mfma_f32_16x16x32_f16(
                            aF[mi], bF[ni], acc[mi][ni], 0, 0, 0);
            }
            __syncthreads();
        }

#pragma unroll
        for (int mi = 0; mi < 4; mi++) {
#pragma unroll
            for (int ni = 0; ni < 8; ni++) {
                int gcol = n0 + wn + ni * 16 + lrow;
                float bias = (kz == 0) ? b2[(size_t)e * CC + gcol] : 0.f;
#pragma unroll
                for (int r = 0; r < 4; r++) {
                    int rowl = m0 + wm + mi * 16 + rbase + r;
                    if (rowl < M) {
                        int lr = rowl - m0;
                        float v = (acc[mi][ni][r] + bias) * wgt[lr];
                        unsafeAtomicAdd(&out[(size_t)toks[lr] * CC + gcol], v);
                    }
                }
            }
        }
    }
}

// ---------------------------------------------------------------------------
extern "C" void kernel_launch(void* const* d_in, const int* in_sizes, int n_in,
                              void* d_out, int out_size, void* d_ws, size_t ws_size,
                              hipStream_t stream)
{
    const float* x  = (const float*)d_in[0];
    const float* gn = (const float*)d_in[1];
    const float* gw = (const float*)d_in[2];
    const float* gb = (const float*)d_in[3];
    const float* w1 = (const float*)d_in[4];
    const float* b1 = (const float*)d_in[5];
    const float* w2 = (const float*)d_in[6];
    const float* b2 = (const float*)d_in[7];
    float* out = (float*)d_out;

    // workspace carve (16B-aligned; ~208 MB)
    char* w = (char*)d_ws;
    int*   counts  = (int*)(w + 0);     // 8 ints
    int*   fill    = (int*)(w + 32);    // 8 ints
    int*   offsets = (int*)(w + 64);    // 9 ints
    float* gsum    = (float*)(w + 128); // 8 floats
    int*   ntl     = (int*)(w + 192);   // 2 ints
    size_t off = 256;
    int*   topk_idx = (int*)(w + off);   off += (size_t)TT * 2 * 4;
    float* topk_w   = (float*)(w + off); off += (size_t)TT * 2 * 4;
    int*   rowtok   = (int*)(w + off);   off += (size_t)TKN * 4;
    float* rweight  = (float*)(w + off); off += (size_t)TKN * 4;
    int*   tiles1   = (int*)(w + off);   off += 4096 * 4;
    int*   tiles2   = (int*)(w + off);   off += 2048 * 4;
    _Float16* xg  = (_Float16*)(w + off); off += (size_t)TKN * CC * 2;      // 16 MB
    _Float16* w1t = (_Float16*)(w + off); off += (size_t)EE * HH * CC * 2;  // 64 MB
    _Float16* w2t = (_Float16*)(w + off); off += (size_t)EE * CC * HH * 2;  // 64 MB
    _Float16* hbuf = (_Float16*)(w + off); off += (size_t)TKN * HH * 2;     // 64 MB

    (void)hipMemsetAsync(d_out, 0, (size_t)out_size * sizeof(float), stream);
    (void)hipMemsetAsync(d_ws, 0, 256, stream);

    gate_kernel<<<TT / 4, 256, 0, stream>>>(x, gn, gw, gb, topk_idx, topk_w,
                                            counts, gsum);
    // w1 [E,C,H] -> w1t [E,H,C];  w2 [E,H,C] -> w2t [E,C,H]
    transpose_f16_kernel<<<dim3(HH / 64, CC / 64, EE), 256, 0, stream>>>(
        w1, w1t, CC, HH);
    transpose_f16_kernel<<<dim3(CC / 64, HH / 64, EE), 256, 0, stream>>>(
        w2, w2t, HH, CC);
    scan_kernel<<<1, 256, 0, stream>>>(counts, offsets, gsum,
                                       out + (size_t)TT * CC, tiles1, tiles2, ntl);
    scatter_kernel<<<TT / 256, 256, 0, stream>>>(topk_idx, topk_w, offsets, fill,
                                                 rowtok, rweight);
    gather_kernel<<<TKN / 2, 256, 0, stream>>>(x, rowtok, xg);
    gemm1_kernel<<<GGRID, 512, 0, stream>>>(xg, w1t, b1, offsets, tiles1, ntl, hbuf);
    gemm2_kernel<<<GGRID, 512, 0, stream>>>(hbuf, w2t, b2, rowtok, rweight,
                                            offsets, tiles2, ntl, out);
}